// Round 15
// baseline (151.475 us; speedup 1.0000x reference)
//
#include <hip/hip_runtime.h>
#include <stdint.h>

typedef __attribute__((ext_vector_type(4))) float floatx4;
typedef __attribute__((ext_vector_type(2))) long longx2;

#define CDIM   256
#define KCODES 1024

__device__ __forceinline__ void gload16(const void* g, void* l) {
    __builtin_amdgcn_global_load_lds((const __attribute__((address_space(1))) void*)g,
                                     (__attribute__((address_space(3))) void*)l, 16, 0, 0);
}
__device__ __forceinline__ unsigned pk4_fp8(float a, float b, float c, float d) {
    int u = __builtin_amdgcn_cvt_pk_fp8_f32(a, b, 0, false);
    u = __builtin_amdgcn_cvt_pk_fp8_f32(c, d, u, true);
    return (unsigned)u;
}

// ---------------- emb -> emb8 [kt][k][64B] fp8(256*e), K-permuted; e_sqs = 4096*e_sq
// byte(kt,k,q,ks,j0) = kt*65536 + k*64 + (q ^ ((k>>1)&3))*16 + ks*8 + j0
// (unchanged — swizzle + loss-zero fold both HW-verified)
__global__ void emb_prep(const float* __restrict__ emb, unsigned char* __restrict__ emb8,
                         float* __restrict__ e_sqs, float* __restrict__ loss) {
    int k = blockIdx.x, l = threadIdx.x;            // 64 lanes
    if (k == 0 && l == 0) *loss = 0.f;
    float4 v = ((const float4*)(emb + (size_t)k * CDIM))[l];
    float s = v.x * v.x + v.y * v.y + v.z * v.z + v.w * v.w;
    int c = l * 4;
    int kt = c >> 6, cl = c & 63;
    int ks = cl >> 5, q = (cl & 31) >> 3, j0 = cl & 7;
    unsigned pk = pk4_fp8(v.x * 256.f, v.y * 256.f, v.z * 256.f, v.w * 256.f);
    *(unsigned*)(emb8 + ((size_t)kt << 16) + (size_t)k * 64 +
                 (q ^ ((k >> 1) & 3)) * 16 + ks * 8 + j0) = pk;
#pragma unroll
    for (int off = 32; off >= 1; off >>= 1) s += __shfl_down(s, off, 64);
    if (l == 0) e_sqs[k] = 4096.f * s;
}

// ---------------- fused kernel: 1024 blocks x 256 threads, 64 positions/block.
// Sized for 32 waves/CU: LDS 18.2KB (union As | Bs dbuf 2x8KB | smG 16KB)
// -> 8 blocks/CU; __launch_bounds__(256,8) targets VGPR<=64 (round-12 analog
// compiled to 56 with heavier live state). 4 waves = 2 pos-halves x 2 code-halves.
// K-chunks of 32 codes; output 4 passes of 32 pos x 128 ch (full 128B lines).
__global__ __launch_bounds__(256, 8)
void vq_fused(const float* __restrict__ z, const float* __restrict__ emb,
              const unsigned char* __restrict__ emb8, const float* __restrict__ e_sqs,
              float* __restrict__ out, float* __restrict__ loss)
{
    __shared__ __align__(16) char smem[18176];
    // union [0, 16384)   : phase0 As [64 pos][256B] | Bs dbuf 2 x [4 kt][32 code][64B]
    //                      | output smG [32 rows][512B] (chunk-swizzled)
    // z2p  [16384,17408) : [4][64] f32 partial z_sq
    // red  [17408,17920) : [64 pos][2 wn] u32
    // sidx [17920,18176) : [64] u32
    unsigned char* As = (unsigned char*)smem;
    float*  z2p    = (float*)(smem + 16384);
    unsigned* red  = (unsigned*)(smem + 17408);
    unsigned* sidx = (unsigned*)(smem + 17920);

    const int tid = threadIdx.x, wave = tid >> 6, lane = tid & 63;
    const int q = lane >> 4, r = lane & 15;
    const int wn = wave & 1, wm = wave >> 1;
    const int m0 = blockIdx.x << 6;
    const int b = m0 >> 10, s0 = m0 & 1023;

    // ---- phase 0: load z, z_sq, convert 16*z -> fp8, K-permute+swizzle into As ----
    {
        const int p = tid & 63, cg = tid >> 6;           // 64 pos x 4 ch-groups of 64
        const float* zb = z + ((size_t)(b * 256 + cg * 64)) * 1024 + s0 + p;
        float ps = 0.f;
#pragma unroll
        for (int qq = 0; qq < 4; ++qq)
#pragma unroll
            for (int ks = 0; ks < 2; ++ks) {
                float v[8];
#pragma unroll
                for (int j = 0; j < 8; ++j) {
                    v[j] = zb[(size_t)(ks * 32 + qq * 8 + j) * 1024];
                    ps = fmaf(v[j], v[j], ps);
                }
                uint2 w;
                w.x = pk4_fp8(16.f * v[0], 16.f * v[1], 16.f * v[2], 16.f * v[3]);
                w.y = pk4_fp8(16.f * v[4], 16.f * v[5], 16.f * v[6], 16.f * v[7]);
                const int pgl = cg * 4 + qq;
                const int pgs = (pgl & 8) | ((pgl & 7) ^ (p & 7));
                *(uint2*)(As + p * 256 + pgs * 16 + ks * 8) = w;
            }
        z2p[cg * 64 + p] = ps;
    }
    __syncthreads();

    // ---- hoist A fragments: wave's 32 positions x 4 kt -> 8 ds_read_b128, once ----
    longx2 faA[4][2];
#pragma unroll
    for (int kt = 0; kt < 4; ++kt)
#pragma unroll
        for (int mt = 0; mt < 2; ++mt) {
            const int p = wm * 32 + mt * 16 + r;
            const int pgl = kt * 4 + q;
            const int pgs = (pgl & 8) | ((pgl & 7) ^ (r & 7));
            faA[kt][mt] = *(const longx2*)(As + p * 256 + pgs * 16);
        }
    __syncthreads();            // faA reads done -> As region becomes Bs dbuf

    // ---- K-loop: 32 chunks of 32 codes, Bs dbuf 2x8KB, prefetch depth 1 ----
    floatx4 acc[2] = {};
    unsigned run[8];
#pragma unroll
    for (int j = 0; j < 8; ++j) run[j] = 0xFFFFFFFFu;

    const int lc = wn * 16 + r;                      // code within chunk
    const int fbq = (q ^ ((r >> 1) & 3)) * 16;       // swizzled fb chunk byte offset
    const int pl0 = tid >> 7, tt = tid & 127;        // staging map: 2 KB per plane-half

    // stage chunk 0 -> buf0 (exposed once; hidden by 8-block/CU TLP)
#pragma unroll
    for (int j = 0; j < 2; ++j) {
        const int pl = pl0 + j * 2;
        gload16(emb8 + (size_t)pl * 65536 + tt * 16,
                (char*)smem + pl * 2048 + tt * 16);
    }

#pragma unroll 1
    for (int t = 0; t < 32; ++t) {
        __syncthreads();        // drains stage(t); all waves past compute(t-1)
        if (t < 31) {           // issue stage(t+1) -> lands under compute(t)
            char* db = (char*)smem + (((t + 1) & 1) << 13);
#pragma unroll
            for (int j = 0; j < 2; ++j) {
                const int pl = pl0 + j * 2;
                gload16(emb8 + (size_t)pl * 65536 + (size_t)(t + 1) * 2048 + tt * 16,
                        db + pl * 2048 + tt * 16);
            }
        }
        const unsigned char* bb = (const unsigned char*)smem + ((t & 1) << 13)
                                  + lc * 64 + fbq;
        const unsigned code = (unsigned)(t * 32 + lc);
        const float fb32 = fmaf(e_sqs[code], 32.f, 524288.f);
#pragma unroll
        for (int kt = 0; kt < 4; ++kt) {
            const longx2 fb = *(const longx2*)(bb + kt * 2048);
#pragma unroll
            for (int mt = 0; mt < 2; ++mt) {
                acc[mt] = __builtin_amdgcn_mfma_f32_16x16x32_fp8_fp8(
                    faA[kt][mt][0], fb[0], acc[mt], 0, 0, 0);
                acc[mt] = __builtin_amdgcn_mfma_f32_16x16x32_fp8_fp8(
                    faA[kt][mt][1], fb[1], acc[mt], 0, 0, 0);
            }
        }
        // fold: v32 = 32*(16384+4096*e_sq) - 64*dot~ ; pack (u32(v32)<<10)|code
#pragma unroll
        for (int mt = 0; mt < 2; ++mt) {
#pragma unroll
            for (int reg = 0; reg < 4; ++reg) {
                float v = fmaf(-64.f, acc[mt][reg], fb32);
                unsigned pk = ((unsigned)v << 10) | code;
                run[(mt << 2) + reg] = min(run[(mt << 2) + reg], pk);
            }
            acc[mt] = (floatx4){0.f, 0.f, 0.f, 0.f};
        }
    }

    // ---- argmin merge: reduce over r (codes), then across code-halves via red ----
#pragma unroll
    for (int j = 0; j < 8; ++j) {
        unsigned pk = run[j];
#pragma unroll
        for (int off = 1; off < 16; off <<= 1)
            pk = min(pk, (unsigned)__shfl_xor((int)pk, off, 64));
        if (r == 0)
            red[(wm * 32 + ((j >> 2) << 4) + (q << 2) + (j & 3)) * 2 + wn] = pk;
    }
    __syncthreads();
    if (tid < 64) {
        unsigned m = min(red[tid * 2 + 0], red[tid * 2 + 1]);
        sidx[tid] = m & 1023u;
        float val = (float)(m >> 10) * (1.f / 32.f);
        float d = (z2p[tid] + z2p[64 + tid]) + (z2p[128 + tid] + z2p[192 + tid])
                + (val - 16384.f) * (1.f / 4096.f);
#pragma unroll
        for (int off = 32; off >= 1; off >>= 1) d += __shfl_down(d, off, 64);
        if (tid == 0) atomicAdd(loss, d * (1.25f / 16777216.f));
    }
    __syncthreads();

    // ---- gather + write z_q: 4 passes of (32 pos x 128 ch) through smG ----
    // smG row = pos, 512B = 128 ch; chunk-swizzled (physical p holds logical
    // (p&24)|((p&7)^(row&7))); out stores are full 128B lines (32 consecutive pos).
#pragma unroll 1
    for (int pass = 0; pass < 4; ++pass) {
        const int rbase = (pass >> 1) << 5;                           // pos half
        const int h = pass & 1;                                       // ch half
#pragma unroll
        for (int i = 0; i < 4; ++i) {
            const int row = i * 8 + wave * 2 + (lane >> 5);           // 0..31
            const unsigned code = sidx[rbase + row];
            const int c = lane & 31;
            const int sc = (c & 24) | ((c & 7) ^ (row & 7));
            gload16(emb + (size_t)code * CDIM + h * 128 + sc * 4,
                    (char*)smem + (i * 8 + wave * 2) * 512 + lane * 16);
        }
        __syncthreads();
        {
            const int s = tid & 31, cg = tid >> 5;                    // 32 pos x 8 ch-grp
            float* ob = out + ((size_t)(b * 256 + h * 128 + cg * 16)) * 1024
                        + s0 + rbase + s;
#pragma unroll
            for (int c4 = 0; c4 < 4; ++c4) {
                const int lc4 = cg * 4 + c4;                          // logical 16B chunk
                const int p16 = (lc4 & 24) | ((lc4 & 7) ^ (s & 7));   // swizzled position
                float4 v = *(const float4*)((const char*)smem + s * 512 + p16 * 16);
                ob[(size_t)(c4 * 4 + 0) * 1024] = v.x;
                ob[(size_t)(c4 * 4 + 1) * 1024] = v.y;
                ob[(size_t)(c4 * 4 + 2) * 1024] = v.z;
                ob[(size_t)(c4 * 4 + 3) * 1024] = v.w;
            }
        }
        if (pass < 3) __syncthreads();
    }
}

extern "C" void kernel_launch(void* const* d_in, const int* in_sizes, int n_in,
                              void* d_out, int out_size, void* d_ws, size_t ws_size,
                              hipStream_t stream)
{
    const float* z   = (const float*)d_in[0];
    const float* emb = (const float*)d_in[1];
    float* out = (float*)d_out;

    unsigned char* emb8 = (unsigned char*)d_ws;           // 256 KB
    float* e_sqs = (float*)((char*)d_ws + 262144);        // 4 KB
    float* loss  = out + 16777216;

    emb_prep<<<KCODES, 64, 0, stream>>>(emb, emb8, e_sqs, loss);
    vq_fused<<<1024, 256, 0, stream>>>(z, emb, emb8, e_sqs, out, loss);
}

// Round 17
// 134.547 us; speedup vs baseline: 1.1258x; 1.1258x over previous
//
#include <hip/hip_runtime.h>
#include <stdint.h>

typedef __attribute__((ext_vector_type(4))) float floatx4;
typedef __attribute__((ext_vector_type(2))) long longx2;

#define CDIM   256
#define KCODES 1024

__device__ __forceinline__ void gload16(const void* g, void* l) {
    __builtin_amdgcn_global_load_lds((const __attribute__((address_space(1))) void*)g,
                                     (__attribute__((address_space(3))) void*)l, 16, 0, 0);
}
__device__ __forceinline__ unsigned pk4_fp8(float a, float b, float c, float d) {
    int u = __builtin_amdgcn_cvt_pk_fp8_f32(a, b, 0, false);
    u = __builtin_amdgcn_cvt_pk_fp8_f32(c, d, u, true);
    return (unsigned)u;
}

// ---------------- emb -> emb8 [kt][k][64B] fp8(256*e), K-permuted; e_sqs = 4096*e_sq
// byte(kt,k,q,ks,j0) = kt*65536 + k*64 + (q ^ ((k>>1)&3))*16 + ks*8 + j0
// (unchanged — swizzle + loss-zero fold both HW-verified)
__global__ void emb_prep(const float* __restrict__ emb, unsigned char* __restrict__ emb8,
                         float* __restrict__ e_sqs, float* __restrict__ loss) {
    int k = blockIdx.x, l = threadIdx.x;            // 64 lanes
    if (k == 0 && l == 0) *loss = 0.f;
    float4 v = ((const float4*)(emb + (size_t)k * CDIM))[l];
    float s = v.x * v.x + v.y * v.y + v.z * v.z + v.w * v.w;
    int c = l * 4;
    int kt = c >> 6, cl = c & 63;
    int ks = cl >> 5, q = (cl & 31) >> 3, j0 = cl & 7;
    unsigned pk = pk4_fp8(v.x * 256.f, v.y * 256.f, v.z * 256.f, v.w * 256.f);
    *(unsigned*)(emb8 + ((size_t)kt << 16) + (size_t)k * 64 +
                 (q ^ ((k >> 1) & 3)) * 16 + ks * 8 + j0) = pk;
#pragma unroll
    for (int off = 32; off >= 1; off >>= 1) s += __shfl_down(s, off, 64);
    if (l == 0) e_sqs[k] = 4096.f * s;
}

// ---------------- fused kernel: 1024 blocks x 512 threads, 64 positions/block.
// Max-occupancy design: LDS 35.6KB (union As 16K | Bs dbuf 2x16K | smG 32K)
// -> 4 blocks/CU x 8 waves = 32 waves/CU (HW max). 8 waves = 4 pos-quarters
// (16 pos) x 2 code-halves. K-chunks of 64 codes (16 staging rounds, round-12
// cadence). __launch_bounds__(512,4): VGPR cap 128, natural ~50 -> no spills
// (rounds 11/15 proved tighter bounds spill).
__global__ __launch_bounds__(512, 4)
void vq_fused(const float* __restrict__ z, const float* __restrict__ emb,
              const unsigned char* __restrict__ emb8, const float* __restrict__ e_sqs,
              float* __restrict__ out, float* __restrict__ loss)
{
    __shared__ __align__(16) char smem[35584];
    // union [0, 32768)   : phase0 As [64 pos][256B] (first 16KB) |
    //                      Bs dbuf 2 x [4 kt][64 code][64B] |
    //                      output smG [32 rows][1KB] (chunk-swizzled)
    // z2p  [32768,34816) : [8][64] f32 partial z_sq
    // red  [34816,35328) : [64 pos][2 wn] u32
    // sidx [35328,35584) : [64] u32
    unsigned char* As = (unsigned char*)smem;
    float*  z2p    = (float*)(smem + 32768);
    unsigned* red  = (unsigned*)(smem + 34816);
    unsigned* sidx = (unsigned*)(smem + 35328);

    const int tid = threadIdx.x, wave = tid >> 6, lane = tid & 63;
    const int q = lane >> 4, r = lane & 15;
    const int wn = wave & 1, wm = wave >> 1;         // 2 code-halves x 4 pos-quarters
    const int m0 = blockIdx.x << 6;
    const int b = m0 >> 10, s0 = m0 & 1023;

    // ---- phase 0: load z, z_sq, convert 16*z -> fp8, K-permute+swizzle into As ----
    // 512 threads = 64 pos x 8 ch-groups of 32 (cg: kt = cg>>1, ks = cg&1)
    {
        const int p = tid & 63, cg = tid >> 6;
        const int ks = cg & 1;
        const float* zb = z + ((size_t)(b * 256 + cg * 32)) * 1024 + s0 + p;
        float ps = 0.f;
#pragma unroll
        for (int qq = 0; qq < 4; ++qq) {
            float v[8];
#pragma unroll
            for (int j = 0; j < 8; ++j) {
                v[j] = zb[(size_t)(qq * 8 + j) * 1024];
                ps = fmaf(v[j], v[j], ps);
            }
            uint2 w;
            w.x = pk4_fp8(16.f * v[0], 16.f * v[1], 16.f * v[2], 16.f * v[3]);
            w.y = pk4_fp8(16.f * v[4], 16.f * v[5], 16.f * v[6], 16.f * v[7]);
            const int pgl = (cg >> 1) * 4 + qq;
            const int pgs = (pgl & 8) | ((pgl & 7) ^ (p & 7));
            *(uint2*)(As + p * 256 + pgs * 16 + ks * 8) = w;
        }
        z2p[cg * 64 + p] = ps;
    }
    __syncthreads();

    // ---- hoist A fragments: wave's 16 positions x 4 kt -> 4 ds_read_b128, once ----
    longx2 faA[4];
#pragma unroll
    for (int kt = 0; kt < 4; ++kt) {
        const int p = wm * 16 + r;
        const int pgl = kt * 4 + q;
        const int pgs = (pgl & 8) | ((pgl & 7) ^ (r & 7));
        faA[kt] = *(const longx2*)(As + p * 256 + pgs * 16);
    }
    __syncthreads();            // faA reads done -> As region becomes Bs dbuf

    // ---- K-loop: 16 chunks of 64 codes, Bs dbuf 2x16KB, prefetch depth 1 ----
    floatx4 acc[2] = {};
    unsigned run[4];
#pragma unroll
    for (int j = 0; j < 4; ++j) run[j] = 0xFFFFFFFFu;

    const int lc = wn * 32 + r;                      // code within chunk (+nt*16)
    const int fbq = (q ^ ((r >> 1) & 3)) * 16;       // swizzled fb chunk byte offset
    const int pl0 = tid >> 8, tt = tid & 255;        // staging: 4KB per kt-plane

    // stage chunk 0 -> buf0 (exposed once; hidden by 32-wave/CU TLP)
#pragma unroll
    for (int j = 0; j < 2; ++j) {
        const int pl = pl0 + j * 2;
        gload16(emb8 + (size_t)pl * 65536 + tt * 16,
                (char*)smem + pl * 4096 + tt * 16);
    }

#pragma unroll 1
    for (int t = 0; t < 16; ++t) {
        __syncthreads();        // drains stage(t); all waves past compute(t-1)
        if (t < 15) {           // issue stage(t+1) -> lands under compute(t)
            char* db = (char*)smem + (((t + 1) & 1) << 14);
#pragma unroll
            for (int j = 0; j < 2; ++j) {
                const int pl = pl0 + j * 2;
                gload16(emb8 + (size_t)pl * 65536 + (size_t)(t + 1) * 4096 + tt * 16,
                        db + pl * 4096 + tt * 16);
            }
        }
        const unsigned char* bb = (const unsigned char*)smem + ((t & 1) << 14);
        float fb32[2];
#pragma unroll
        for (int nt = 0; nt < 2; ++nt)
            fb32[nt] = fmaf(e_sqs[t * 64 + lc + nt * 16], 32.f, 524288.f);
        longx2 fb[4][2];
#pragma unroll
        for (int kt = 0; kt < 4; ++kt)
#pragma unroll
            for (int nt = 0; nt < 2; ++nt)
                fb[kt][nt] = *(const longx2*)(bb + kt * 4096 + (lc + nt * 16) * 64 + fbq);
#pragma unroll
        for (int kt = 0; kt < 4; ++kt)
#pragma unroll
            for (int nt = 0; nt < 2; ++nt) {
                acc[nt] = __builtin_amdgcn_mfma_f32_16x16x32_fp8_fp8(
                    faA[kt][0], fb[kt][nt][0], acc[nt], 0, 0, 0);
                acc[nt] = __builtin_amdgcn_mfma_f32_16x16x32_fp8_fp8(
                    faA[kt][1], fb[kt][nt][1], acc[nt], 0, 0, 0);
            }
        // fold: v32 = 32*(16384+4096*e_sq) - 64*dot~ ; pack (u32(v32)<<10)|code;
        // min over the 2 code-sub-tiles immediately (run is per-POSITION).
#pragma unroll
        for (int reg = 0; reg < 4; ++reg) {
            unsigned best = run[reg];
#pragma unroll
            for (int nt = 0; nt < 2; ++nt) {
                const unsigned code = (unsigned)(t * 64 + lc + nt * 16);
                float v = fmaf(-64.f, acc[nt][reg], fb32[nt]);
                best = min(best, ((unsigned)v << 10) | code);
            }
            run[reg] = best;
        }
#pragma unroll
        for (int nt = 0; nt < 2; ++nt) acc[nt] = (floatx4){0.f, 0.f, 0.f, 0.f};
    }

    // ---- argmin merge: reduce over r (16 codes), then across wn halves via red ----
#pragma unroll
    for (int j = 0; j < 4; ++j) {
        unsigned pk = run[j];
#pragma unroll
        for (int off = 1; off < 16; off <<= 1)
            pk = min(pk, (unsigned)__shfl_xor((int)pk, off, 64));
        if (r == 0)
            red[(wm * 16 + q * 4 + j) * 2 + wn] = pk;   // pos = wm*16 + q*4 + reg
    }
    __syncthreads();
    if (tid < 64) {
        unsigned m = min(red[tid * 2 + 0], red[tid * 2 + 1]);
        sidx[tid] = m & 1023u;
        float val = (float)(m >> 10) * (1.f / 32.f);
        float d = ((z2p[tid] + z2p[64 + tid]) + (z2p[128 + tid] + z2p[192 + tid]))
                + ((z2p[256 + tid] + z2p[320 + tid]) + (z2p[384 + tid] + z2p[448 + tid]))
                + (val - 16384.f) * (1.f / 4096.f);
#pragma unroll
        for (int off = 32; off >= 1; off >>= 1) d += __shfl_down(d, off, 64);
        if (tid == 0) atomicAdd(loss, d * (1.25f / 16777216.f));
    }
    __syncthreads();

    // ---- gather + write z_q: 2 passes of 32 rows x 1KB through smG ----
    // physical chunk `lane` of row holds logical (lane&56)|((lane&7)^(row&7));
    // writer applies the same involution. Full 128B out lines (32 consec pos).
#pragma unroll 1
    for (int pass = 0; pass < 2; ++pass) {
        const int rbase = pass << 5;
#pragma unroll
        for (int i = 0; i < 4; ++i) {
            const int row = wave * 4 + i;                             // 0..31
            const unsigned code = sidx[rbase + row];
            const int src_chunk = (lane & 56) | ((lane & 7) ^ (row & 7));
            gload16(emb + (size_t)code * CDIM + src_chunk * 4,
                    (char*)smem + row * 1024 + lane * 16);
        }
        __syncthreads();
        {
            const int s = tid & 31, cg = tid >> 5;                    // 32 pos x 16 ch-grp
            float* ob = out + ((size_t)(b * 256 + cg * 16)) * 1024 + s0 + rbase + s;
#pragma unroll
            for (int c4 = 0; c4 < 4; ++c4) {
                const int lc4 = cg * 4 + c4;                          // logical 16B chunk
                const int p16 = (lc4 & 56) | ((lc4 & 7) ^ (s & 7));   // swizzled position
                float4 v = *(const float4*)((const char*)smem + s * 1024 + p16 * 16);
                ob[(size_t)(c4 * 4 + 0) * 1024] = v.x;
                ob[(size_t)(c4 * 4 + 1) * 1024] = v.y;
                ob[(size_t)(c4 * 4 + 2) * 1024] = v.z;
                ob[(size_t)(c4 * 4 + 3) * 1024] = v.w;
            }
        }
        if (pass == 0) __syncthreads();
    }
}

extern "C" void kernel_launch(void* const* d_in, const int* in_sizes, int n_in,
                              void* d_out, int out_size, void* d_ws, size_t ws_size,
                              hipStream_t stream)
{
    const float* z   = (const float*)d_in[0];
    const float* emb = (const float*)d_in[1];
    float* out = (float*)d_out;

    unsigned char* emb8 = (unsigned char*)d_ws;           // 256 KB
    float* e_sqs = (float*)((char*)d_ws + 262144);        // 4 KB
    float* loss  = out + 16777216;

    emb_prep<<<KCODES, 64, 0, stream>>>(emb, emb8, e_sqs, loss);
    vq_fused<<<1024, 512, 0, stream>>>(z, emb, emb8, e_sqs, out, loss);
}